// Round 11
// baseline (121.893 us; speedup 1.0000x reference)
//
#include <hip/hip_runtime.h>

#define NQ   12
#define DIM  4096
#define NL   4
#define BLK  512

typedef unsigned short u16;
typedef unsigned int   u32;
typedef float f2 __attribute__((ext_vector_type(2)));

// ---------- cheap GF(2) helpers ----------
static constexpr int par(u32 v){ return __builtin_popcount(v)&1; }
static constexpr int hb(u16 v){ for(int i=11;i>=0;--i) if((v>>i)&1u) return i; return -1; }

// ---------- compile-time GF(2) linear algebra for the CNOT-chain permutation ----------
struct L12 { u16 b[NQ]; };

static constexpr u32 lap(const L12& A, u32 x){ u32 r=0; for(int p=0;p<NQ;++p) if((x>>p)&1u) r^=A.b[p]; return r; }
static constexpr L12 lcomp(const L12& A, const L12& B){ L12 r{}; for(int p=0;p<NQ;++p) r.b[p]=(u16)lap(A,(u32)B.b[p]); return r; }
static constexpr L12 lident(){ L12 r{}; for(int p=0;p<NQ;++p) r.b[p]=(u16)(1u<<p); return r; }

static constexpr u32 applyT(u32 i){
  i ^= ((i>>0)&1u) << 11;                            // CNOT(11,0): bit11 ^= bit0
  for(int q=10;q>=0;--q){ int pc2=11-q, pt=10-q; i ^= ((i>>pc2)&1u) << pt; }
  return i;
}
static constexpr L12 lT(){ L12 t{}; for(int p=0;p<NQ;++p) t.b[p]=(u16)applyT(1u<<p); return t; }

static constexpr L12 linv(const L12& A){              // GF(2) Gauss-Jordan
  u16 v[NQ]={}; u16 u[NQ]={};
  for(int p=0;p<NQ;++p){ v[p]=A.b[p]; u[p]=(u16)(1u<<p); }
  for(int t=0;t<NQ;++t){
    int p=t; while(!((v[p]>>t)&1u)) ++p;
    u16 tv=v[p]; v[p]=v[t]; v[t]=tv; u16 tu=u[p]; u[p]=u[t]; u[t]=tu;
    for(int k=0;k<NQ;++k) if(k!=t && ((v[k]>>t)&1u)){ v[k]^=v[t]; u[k]^=u[t]; }
  }
  L12 r{}; for(int p=0;p<NQ;++p) r.b[p]=u[p]; return r;
}
static constexpr L12 ltr(const L12& A){
  L12 r{}; for(int p=0;p<NQ;++p) for(int q=0;q<NQ;++q) if((A.b[p]>>q)&1u) r.b[q]=(u16)(r.b[q]|(1u<<p));
  return r;
}

struct Tables {
  u16 cm[12][16];   // [step][combo] xor-offsets spanning the 4 gate masks
  u16 wg[12][4];    // [step][gate] parity mask: a0/a1 role selector
  u16 wexp[NQ];     // final <Z> parity masks: rows of (T^4)^{-T}
};

static constexpr Tables make_tables(){
  Tables tb{};
  const L12 T   = lT();
  const L12 Tit = ltr(linv(T));   // T^{-T}
  L12 A = lident();               // A_l = T^l   (stored_index = A_l(true_index))
  L12 W = lident();               // W_l = A_l^{-T}
  for(int l=0;l<NL;++l){
    for(int g=0;g<3;++g){
      const int st = l*3+g;
      u16 mm[4]={0,0,0,0};
      for(int i=0;i<4;++i){ mm[i]=A.b[4*g+i]; tb.wg[st][i]=W.b[4*g+i]; }
      for(int c=0;c<16;++c){ u32 m=0; for(int i=0;i<4;++i) if((c>>i)&1) m^=mm[i]; tb.cm[st][c]=(u16)m; }
    }
    A = lcomp(A, T);
    W = lcomp(W, Tit);
  }
  for(int p=0;p<NQ;++p) tb.wexp[p]=W.b[p];
  return tb;
}

// ---------- LDS swizzle: slot = j ^ fold(j>>4), fold linear over GF(2) ----------
static constexpr u16 UIMG[12] = {1,2,4,8, 3,5,6,7, 9,10,11,13};
static constexpr u32 swz(u32 j){
  u32 f=0;
  for(int k=4;k<12;++k) if((j>>k)&1u) f ^= (u32)UIMG[k];
  return j ^ (f & 15u);
}

struct Ech { u16 s[12]; };
static constexpr u16 ered(const Ech& e, u16 x){
  while(x){
    const int lb=hb(x);
    if(e.s[lb]) x=(u16)(x^e.s[lb]); else break;
  }
  return x;
}
static constexpr bool eadd(Ech& e, u16 x){
  x=ered(e,x); if(!x) return false;
  e.s[hb(x)]=x; return true;
}

// ---------- trip tables: 16 trips × 3 gates (gates g=3t..3t+2, gate g: step g/4, idx g%4) ----------
struct Trip {
  u32 lane_c[9];   // tid bit k -> swz(e_f)<<3 | roleNib(3b)<<28
  u32 raw9[9];     // raw lattice vectors
  u32 smb[3];      // swz(M_k)<<3
  u32 rawm[3];     // raw M_k
  u32 scmb[8];     // swz(combo)<<3
  u32 cinv[3];     // C^{-1} rows (3-bit) when cok
  u32 rho[3];      // per-gate compile-time role bit over combos c
  bool cok;        // role system invertible -> plain path
};

static constexpr Trip make_trip(int t){
  Trip r{};
  const Tables tb = make_tables();
  u16 M[3]={}, w[3]={};
  for(int j=0;j<3;++j){
    const int g=3*t+j, st=g>>2, qi=g&3;
    M[j]=tb.cm[st][(u32)1<<qi]; w[j]=tb.wg[st][qi];
  }
  // free (non-pivot) positions of span{M}
  Ech em{};
  for(int j=0;j<3;++j) eadd(em,M[j]);
  bool isp[12]={};
  for(int b2=0;b2<12;++b2) if(em.s[b2]) isp[b2]=true;
  int np[12]={}; int nn=0;
  for(int p=0;p<12;++p) if(!isp[p]) np[nn++]=p;     // 9 positions (rank-3 masks)
  // choose 4 whose swz bank-pair images have rank 4 (16-lane phase conflict floor)
  int s0=0,s1=1,s2=2,s3=3; bool found=false;
  for(int i0=0;i0<nn&&!found;++i0)for(int i1=i0+1;i1<nn&&!found;++i1)
  for(int i2=i1+1;i2<nn&&!found;++i2)for(int i3=i2+1;i3<nn&&!found;++i3){
    u16 img[4]={(u16)(swz((u32)1<<np[i0])&15u),(u16)(swz((u32)1<<np[i1])&15u),
                (u16)(swz((u32)1<<np[i2])&15u),(u16)(swz((u32)1<<np[i3])&15u)};
    u16 bas[4]={0,0,0,0}; int rk=0;
    for(int ii=0;ii<4;++ii){
      u16 x=img[ii];
      while(x){
        int hbx=3; while(hbx>0 && !((x>>hbx)&1)) --hbx;
        if(bas[hbx]) x=(u16)(x^bas[hbx]); else { bas[hbx]=x; ++rk; x=0; }
      }
    }
    if(rk==4){ s0=i0;s1=i1;s2=i2;s3=i3; found=true; }
  }
  int ord[9]={}; ord[0]=s0;ord[1]=s1;ord[2]=s2;ord[3]=s3;
  int rp=4;
  for(int j=0;j<nn;++j){ if(j!=s0&&j!=s1&&j!=s2&&j!=s3) ord[rp++]=j; }
  for(int k=0;k<9;++k){
    const int f=np[ord[k]];
    u32 nib=0;
    for(int i=0;i<3;++i) nib |= (u32)((w[i]>>f)&1u)<<i;
    r.lane_c[k]=(swz((u32)1<<f)<<3)|(nib<<28);
    r.raw9[k]=(u32)1<<f;
  }
  for(int k=0;k<3;++k){ r.smb[k]=swz((u32)M[k])<<3; r.rawm[k]=(u32)M[k]; }
  for(int c=0;c<8;++c){
    u32 m=0;
    for(int j=0;j<3;++j) if((c>>j)&1) m^=(u32)M[j];
    r.scmb[c]=swz(m)<<3;
  }
  // beta[i] bit k = <M_k, w_i>; C = beta (diag 1); invert over GF(2)
  u32 beta[3]={};
  for(int i=0;i<3;++i){ u32 row=0; for(int k=0;k<3;++k) row|=(u32)par((u32)(M[k]&w[i]))<<k; beta[i]=row; }
  u32 rows[3]={ beta[0]|(1u<<3), beta[1]|(2u<<3), beta[2]|(4u<<3) };
  bool ok=true;
  for(int col=0;col<3;++col){
    int pv=-1;
    for(int rr=col;rr<3;++rr) if((rows[rr]>>col)&1u){pv=rr;break;}
    if(pv<0){ok=false;break;}
    u32 tt=rows[col]; rows[col]=rows[pv]; rows[pv]=tt;
    for(int rr=0;rr<3;++rr) if(rr!=col&&((rows[rr]>>col)&1u)) rows[rr]^=rows[col];
  }
  r.cok=ok;
  if(ok) for(int k=0;k<3;++k) r.cinv[k]=(rows[k]>>3)&7u;
  // rho[i] bit c = parity_{j!=i, c_j} beta_ij (compile-time role residue)
  for(int i=0;i<3;++i){
    u32 m=0;
    for(int c=0;c<8;++c){
      int v=0;
      for(int j=0;j<3;++j) if(j!=i && ((c>>j)&1)) v ^= (int)((beta[i]>>j)&1u);
      m |= (u32)v<<c;
    }
    r.rho[i]=m;
  }
  return r;
}

static constexpr Trip TRIPS[16] = {
  make_trip(0), make_trip(1), make_trip(2), make_trip(3),
  make_trip(4), make_trip(5), make_trip(6), make_trip(7),
  make_trip(8), make_trip(9), make_trip(10), make_trip(11),
  make_trip(12), make_trip(13), make_trip(14), make_trip(15)
};

// ---------- readout tables (trip 15 = step 11 gates 1,2,3) ----------
struct RD { u16 pm[12]; u16 mu[12]; };
static constexpr RD make_rd(){
  RD r{};
  const Tables tb=make_tables();
  u16 M[3]={};
  for(int j=0;j<3;++j) M[j]=tb.cm[11][(u32)1<<(1+j)];
  for(int q=0;q<12;++q){
    r.pm[q]=tb.wexp[11-q];
    u32 m=0;
    for(int j=0;j<3;++j) m|=(u32)par((u32)(M[j]&tb.wexp[11-q]))<<j;
    r.mu[q]=(u16)m;
  }
  return r;
}
static constexpr RD RDT = make_rd();

__device__ __forceinline__ float fx(float a, u32 m){ return __uint_as_float(__float_as_uint(a)^m); }

// ---------- one gate (G = 3*TI+J, combo bit J) ----------
// gw[G] = {tan(ty/4), sin(ty/2), tan(tz/2), sin(tz)}; gwH[G] = {tan(tz/4), sin(tz/2),-,-}
template<int TI, int J>
__device__ __forceinline__ void one_gate(f2 (&a)[8], const float4* __restrict__ gw,
                                         const float4* __restrict__ gwH, u32 nib){
  constexpr int G = 3*TI+J;
  constexpr bool WITHW = (G < 36);          // layer 3 (steps 9-11): RZ dropped
  const float4 g = gw[G];
  if constexpr (TRIPS[TI].cok){
    // roles pre-zeroed by rep shift; residual rho = compile-time index swap
#pragma unroll
    for(int c=0;c<8;++c){
      if((c>>J)&1) continue;
      const int c1=c|(1<<J);
      const int p = ((TRIPS[TI].rho[J]>>c)&1u) ? c1 : c;
      const int q = ((TRIPS[TI].rho[J]>>c)&1u) ? c : c1;
      f2 u,v;
      u.x=fmaf(-g.x,a[q].x,a[p].x); u.y=fmaf(-g.x,a[q].y,a[p].y);
      v.x=fmaf( g.y,u.x,a[q].x);    v.y=fmaf( g.y,u.y,a[q].y);
      a[p].x=fmaf(-g.x,v.x,u.x);    a[p].y=fmaf(-g.x,v.y,u.y);
      if(WITHW){ const float tt=fmaf(-g.z,v.y,v.x); v.y=fmaf(g.w,tt,v.y); v.x=fmaf(-g.z,v.y,tt); }
      a[q]=v;
    }
  } else {
    // half-angle path: runtime role bit R (sign-xored constants), rho via modifiers,
    // per-gate global phase e^{i tz/2} dropped (|amp|^2 readout)
    const u32 Rm = ((nib>>J)&1u)<<31;
    const float tg=fx(g.x,Rm), sg=fx(g.y,Rm);
    float t2=0.f, s2=0.f;
    if constexpr (WITHW){
      const float4 h=gwH[G];
      t2=fx(h.x,Rm^0x80000000u); s2=fx(h.y,Rm^0x80000000u);
    }
#pragma unroll
    for(int c=0;c<8;++c){
      if((c>>J)&1) continue;
      const int c1=c|(1<<J);
      if(((TRIPS[TI].rho[J]>>c)&1u)==0){
        f2 u,v;
        u.x=fmaf(-tg,a[c1].x,a[c].x); u.y=fmaf(-tg,a[c1].y,a[c].y);
        v.x=fmaf( sg,u.x,a[c1].x);    v.y=fmaf( sg,u.y,a[c1].y);
        a[c].x=fmaf(-tg,v.x,u.x);     a[c].y=fmaf(-tg,v.y,u.y);
        a[c1]=v;
        if(WITHW){
          float tt=fmaf(-t2,a[c].y,a[c].x);   a[c].y=fmaf( s2,tt,a[c].y);   a[c].x=fmaf(-t2,a[c].y,tt);
          tt=fmaf( t2,a[c1].y,a[c1].x);       a[c1].y=fmaf(-s2,tt,a[c1].y); a[c1].x=fmaf( t2,a[c1].y,tt);
        }
      } else {
        f2 u,v;
        u.x=fmaf( tg,a[c1].x,a[c].x); u.y=fmaf( tg,a[c1].y,a[c].y);
        v.x=fmaf(-sg,u.x,a[c1].x);    v.y=fmaf(-sg,u.y,a[c1].y);
        a[c].x=fmaf( tg,v.x,u.x);     a[c].y=fmaf( tg,v.y,u.y);
        a[c1]=v;
        if(WITHW){
          float tt=fmaf( t2,a[c].y,a[c].x);   a[c].y=fmaf(-s2,tt,a[c].y);   a[c].x=fmaf( t2,a[c].y,tt);
          tt=fmaf(-t2,a[c1].y,a[c1].x);       a[c1].y=fmaf( s2,tt,a[c1].y); a[c1].x=fmaf(-t2,a[c1].y,tt);
        }
      }
    }
  }
}

// ---------- middle trip: read 8 -> 3 gates -> write 8 -> barrier ----------
template<int TI>
__device__ __forceinline__ void trip_mid(const u32* msk, char* lds,
                                         const float4* __restrict__ gw,
                                         const float4* __restrict__ gwH){
  u32 acc=0;
#pragma unroll
  for(int k=0;k<9;++k) acc ^= TRIPS[TI].lane_c[k]&msk[k];
  const u32 nib = acc>>28;
  u32 base = acc & 0x0FFFFFFFu;
  if constexpr (TRIPS[TI].cok){
#pragma unroll
    for(int k=0;k<3;++k){
      const u32 sk=(u32)(__popc(TRIPS[TI].cinv[k]&nib)&1);
      base ^= TRIPS[TI].smb[k]&(0u-sk);
    }
  }
  f2 a[8]; u32 ad[8];
#pragma unroll
  for(int c=0;c<8;++c){ ad[c]=base^TRIPS[TI].scmb[c]; a[c]=*(const f2*)(lds+ad[c]); }
  one_gate<TI,0>(a,gw,gwH,nib);
  one_gate<TI,1>(a,gw,gwH,nib);
  one_gate<TI,2>(a,gw,gwH,nib);
#pragma unroll
  for(int c=0;c<8;++c){ *(f2*)(lds+ad[c])=a[c]; }
  __syncthreads();
}

__global__ void prep_kernel(const float* __restrict__ w, float4* __restrict__ gw,
                            float4* __restrict__ gwH){
  const int t = threadIdx.x;
  if(t < NL*NQ){
    const int l=t/NQ, p=t%NQ, q=(NQ-1)-p;
    const float ty=w[(l*NQ+q)*2+0], tz=w[(l*NQ+q)*2+1];
    gw[t]=make_float4(tanf(0.25f*ty), sinf(0.5f*ty), tanf(0.5f*tz), sinf(tz));
    gwH[t]=make_float4(tanf(0.25f*tz), sinf(0.5f*tz), 0.f, 0.f);
  }
}

__global__ __launch_bounds__(BLK, 8) void qsim_kernel(const float* __restrict__ x,
                                                      const float4* __restrict__ gw,
                                                      const float4* __restrict__ gwH,
                                                      float* __restrict__ out)
{
  __shared__ f2 st2[DIM];              // exactly 32768 B -> 4 blocks x 8 waves = 32 waves/CU
  char* lds = (char*)st2;
  const int tid = threadIdx.x;
  const int bb  = blockIdx.x;

  u32 msk[9];
#pragma unroll
  for(int k=0;k<9;++k) msk[k]=0u-((u32)(tid>>k)&1u);

  // ---- trip 0 (step-0 gates 0-2; masks {1,2,4}; reps 8-aligned -> global float4 loads) ----
  {
    u32 acc=0, raw=0;
#pragma unroll
    for(int k=0;k<9;++k){ acc ^= TRIPS[0].lane_c[k]&msk[k]; raw ^= TRIPS[0].raw9[k]&msk[k]; }
    const u32 base = acc & 0x0FFFFFFFu;   // trip0: roles identically zero (W0=I, lattice >= bit3)
    f2 a[8];
    const float* xr = x + (size_t)bb*DIM + raw;
    const float4 v0 = *reinterpret_cast<const float4*>(xr);
    const float4 v1 = *reinterpret_cast<const float4*>(xr+4);
    a[0]=(f2){v0.x,0.f}; a[1]=(f2){v0.y,0.f}; a[2]=(f2){v0.z,0.f}; a[3]=(f2){v0.w,0.f};
    a[4]=(f2){v1.x,0.f}; a[5]=(f2){v1.y,0.f}; a[6]=(f2){v1.z,0.f}; a[7]=(f2){v1.w,0.f};
    one_gate<0,0>(a,gw,gwH,0u);
    one_gate<0,1>(a,gw,gwH,0u);
    one_gate<0,2>(a,gw,gwH,0u);
#pragma unroll
    for(int c=0;c<8;++c){ *(f2*)(lds + (base^TRIPS[0].scmb[c])) = a[c]; }
    __syncthreads();
  }

  // ---- trips 1..14 ----
  trip_mid<1 >(msk,lds,gw,gwH);
  trip_mid<2 >(msk,lds,gw,gwH);
  trip_mid<3 >(msk,lds,gw,gwH);
  trip_mid<4 >(msk,lds,gw,gwH);
  trip_mid<5 >(msk,lds,gw,gwH);
  trip_mid<6 >(msk,lds,gw,gwH);
  trip_mid<7 >(msk,lds,gw,gwH);
  trip_mid<8 >(msk,lds,gw,gwH);
  trip_mid<9 >(msk,lds,gw,gwH);
  trip_mid<10>(msk,lds,gw,gwH);
  trip_mid<11>(msk,lds,gw,gwH);
  trip_mid<12>(msk,lds,gw,gwH);
  trip_mid<13>(msk,lds,gw,gwH);
  trip_mid<14>(msk,lds,gw,gwH);

  // ---- trip 15 (step-11 gates 1-3) + fused Walsh readout (no write-back) ----
  {
    u32 acc=0, urep=0;
#pragma unroll
    for(int k=0;k<9;++k){ acc ^= TRIPS[15].lane_c[k]&msk[k]; urep ^= TRIPS[15].raw9[k]&msk[k]; }
    const u32 nib = acc>>28;
    u32 base = acc & 0x0FFFFFFFu;
    if constexpr (TRIPS[15].cok){
#pragma unroll
      for(int k=0;k<3;++k){
        const u32 sk=(u32)(__popc(TRIPS[15].cinv[k]&nib)&1);
        const u32 mi=0u-sk;
        base ^= TRIPS[15].smb[k]&mi; urep ^= TRIPS[15].rawm[k]&mi;
      }
    }
    f2 a[8];
#pragma unroll
    for(int c=0;c<8;++c){ a[c]=*(const f2*)(lds + (base^TRIPS[15].scmb[c])); }
    one_gate<15,0>(a,gw,gwH,nib);
    one_gate<15,1>(a,gw,gwH,nib);
    one_gate<15,2>(a,gw,gwH,nib);

    float pr[8];
#pragma unroll
    for(int c=0;c<8;++c) pr[c]=fmaf(a[c].x,a[c].x, a[c].y*a[c].y);
    // Walsh-Hadamard over the 3 combo bits
#pragma unroll
    for(int b=1;b<8;b<<=1){
#pragma unroll
      for(int c=0;c<8;++c){
        if(c&b) continue;
        const float u=pr[c], v=pr[c|b];
        pr[c]=u+v; pr[c|b]=u-v;
      }
    }
    float accq[12];
#pragma unroll
    for(int q=0;q<12;++q){
      const u32 sb = ((u32)__popc(urep & (u32)RDT.pm[q]) & 1u)<<31;
      accq[q]=__uint_as_float(__float_as_uint(pr[RDT.mu[q]])^sb);
    }
    float nrm2 = pr[0];
#pragma unroll
    for(int o=32;o;o>>=1){
      nrm2 += __shfl_xor(nrm2,o);
#pragma unroll
      for(int q=0;q<12;++q) accq[q]+=__shfl_xor(accq[q],o);
    }
    __syncthreads();                      // all waves done reading trip-15 data
    float* wredf = (float*)lds;           // alias reduction buffer into state LDS
    const int wid=tid>>6;                 // 8 waves
    if((tid&63)==0){
#pragma unroll
      for(int q=0;q<12;++q) wredf[wid*13+q]=accq[q];
      wredf[wid*13+12]=nrm2;
    }
    __syncthreads();
    if(tid<NQ){
      float s0=0.f, sn=0.f;
#pragma unroll
      for(int wv=0;wv<8;++wv){ s0+=wredf[wv*13+tid]; sn+=wredf[wv*13+12]; }
      out[(size_t)bb*NQ+tid]=s0/sn;
    }
  }
}

extern "C" void kernel_launch(void* const* d_in, const int* in_sizes, int n_in,
                              void* d_out, int out_size, void* d_ws, size_t ws_size,
                              hipStream_t stream) {
  const float* x = (const float*)d_in[0];
  const float* w = (const float*)d_in[1];
  float* out = (float*)d_out;
  float4* gw  = (float4*)d_ws;
  float4* gwH = gw + NL*NQ;
  const int B = in_sizes[0] / DIM;
  prep_kernel<<<1, 64, 0, stream>>>(w, gw, gwH);
  qsim_kernel<<<B, BLK, 0, stream>>>(x, gw, gwH, out);
}